// Round 4
// baseline (554.395 us; speedup 1.0000x reference)
//
#include <hip/hip_runtime.h>
#include <math.h>

#define N_CELLS 8192
#define DIM 512
#define TILE 128

typedef float f32x4 __attribute__((ext_vector_type(4)));
typedef short s16x8 __attribute__((ext_vector_type(8)));

#define AS1U(p) ((const __attribute__((address_space(1))) unsigned int*)(p))
#define AS3U(p) ((__attribute__((address_space(3))) unsigned int*)(p))

// ---------- helpers: order-preserving float<->uint key ----------
__device__ __forceinline__ unsigned fkey(float f) {
    unsigned u = __float_as_uint(f);
    return (u & 0x80000000u) ? ~u : (u | 0x80000000u);
}
__device__ __forceinline__ float finv(unsigned k) {
    unsigned u = (k & 0x80000000u) ? (k ^ 0x80000000u) : ~k;
    return __uint_as_float(u);
}
// round-to-nearest-even fp32 -> bf16 bits
__device__ __forceinline__ unsigned short f2bf_bits(float x) {
    unsigned u = __float_as_uint(x);
    u += 0x7fffu + ((u >> 16) & 1u);
    return (unsigned short)(u >> 16);
}

// ---------- kernel A: squared norms (exact fp32) + zero output ----------
__global__ __launch_bounds__(256) void norms_kernel(const float* __restrict__ E,
                                                    float* __restrict__ norms,
                                                    float* __restrict__ out) {
    if (blockIdx.x == 0 && threadIdx.x == 0) out[0] = 0.0f;
    const int wave = threadIdx.x >> 6, lane = threadIdx.x & 63;
    const int row = blockIdx.x * 4 + wave;
    const float4* e4 = (const float4*)(E + (size_t)row * DIM);
    float4 a = e4[lane], b = e4[lane + 64];
    float s = a.x*a.x + a.y*a.y + a.z*a.z + a.w*a.w
            + b.x*b.x + b.y*b.y + b.z*b.z + b.w*b.w;
    #pragma unroll
    for (int off = 32; off > 0; off >>= 1) s += __shfl_down(s, off, 64);
    if (lane == 0) norms[row] = s;
}

// ---------- kernel A2: fp32 -> (hi, lo) bf16 split ----------
__global__ __launch_bounds__(256) void convert_kernel(const float* __restrict__ E,
                                                      unsigned short* __restrict__ Eh,
                                                      unsigned short* __restrict__ El) {
    const int idx = (blockIdx.x * 256 + threadIdx.x) * 4;
    float4 v = *(const float4*)(E + idx);
    ushort4 h, l;
    h.x = f2bf_bits(v.x); h.y = f2bf_bits(v.y); h.z = f2bf_bits(v.z); h.w = f2bf_bits(v.w);
    l.x = f2bf_bits(v.x - __uint_as_float((unsigned)h.x << 16));
    l.y = f2bf_bits(v.y - __uint_as_float((unsigned)h.y << 16));
    l.z = f2bf_bits(v.z - __uint_as_float((unsigned)h.z << 16));
    l.w = f2bf_bits(v.w - __uint_as_float((unsigned)h.w << 16));
    *(ushort4*)(Eh + idx) = h;
    *(ushort4*)(El + idx) = l;
}

// ---------- kernel B: MFMA split-bf16 distance GEMM (row chunk) ----------
// dot(e_i,e_j) ~= hi.hi + hi.lo + lo.hi (lo.lo dropped, ~1e-4 abs).
__device__ __forceinline__ s16x8 frag_ld(const unsigned short* tile, int rowbase, int lane) {
    const int row = rowbase + (lane & 15);
    const int k8 = (lane >> 4) * 8;
    return *(const s16x8*)(tile + row * 32 + k8);
}

__global__ __launch_bounds__(256) void dist_mfma_kernel(const unsigned short* __restrict__ Eh,
                                                        const unsigned short* __restrict__ El,
                                                        const float* __restrict__ norms,
                                                        float* __restrict__ Dm,
                                                        int r0) {
    __shared__ unsigned short Ah[TILE * 32];
    __shared__ unsigned short Al[TILE * 32];
    __shared__ unsigned short Bh[TILE * 32];
    __shared__ unsigned short Bl[TILE * 32];

    const int t = threadIdx.x;
    const int lane = t & 63;
    const int w = t >> 6;
    const int wr = w >> 1, wc = w & 1;

    const int arow = r0 + blockIdx.y * TILE;   // global rows (i)
    const int brow = blockIdx.x * TILE;        // global cols (j)

    const int srow = t >> 2;        // 0..63
    const int sk = (t & 3) * 8;

    f32x4 acc[4][4];
    #pragma unroll
    for (int a = 0; a < 4; a++)
        #pragma unroll
        for (int b = 0; b < 4; b++)
            acc[a][b] = (f32x4){0.f, 0.f, 0.f, 0.f};

    for (int k0 = 0; k0 < DIM; k0 += 32) {
        __syncthreads();
        {
            const size_t ga0 = (size_t)(arow + srow) * DIM + k0 + sk;
            const size_t gb0 = (size_t)(brow + srow) * DIM + k0 + sk;
            const size_t stp = (size_t)64 * DIM;
            __builtin_amdgcn_global_load_lds(AS1U(Eh + ga0),       AS3U((char*)Ah + t*16),        16, 0, 0);
            __builtin_amdgcn_global_load_lds(AS1U(Eh + ga0 + stp), AS3U((char*)Ah + 4096 + t*16), 16, 0, 0);
            __builtin_amdgcn_global_load_lds(AS1U(El + ga0),       AS3U((char*)Al + t*16),        16, 0, 0);
            __builtin_amdgcn_global_load_lds(AS1U(El + ga0 + stp), AS3U((char*)Al + 4096 + t*16), 16, 0, 0);
            __builtin_amdgcn_global_load_lds(AS1U(Eh + gb0),       AS3U((char*)Bh + t*16),        16, 0, 0);
            __builtin_amdgcn_global_load_lds(AS1U(Eh + gb0 + stp), AS3U((char*)Bh + 4096 + t*16), 16, 0, 0);
            __builtin_amdgcn_global_load_lds(AS1U(El + gb0),       AS3U((char*)Bl + t*16),        16, 0, 0);
            __builtin_amdgcn_global_load_lds(AS1U(El + gb0 + stp), AS3U((char*)Bl + 4096 + t*16), 16, 0, 0);
        }
        __syncthreads();

        s16x8 ah[4], al[4], bh[4], bl[4];
        #pragma unroll
        for (int tm = 0; tm < 4; tm++) {
            ah[tm] = frag_ld(Ah, wr * 64 + tm * 16, lane);
            al[tm] = frag_ld(Al, wr * 64 + tm * 16, lane);
        }
        #pragma unroll
        for (int tn = 0; tn < 4; tn++) {
            bh[tn] = frag_ld(Bh, wc * 64 + tn * 16, lane);
            bl[tn] = frag_ld(Bl, wc * 64 + tn * 16, lane);
        }
        #pragma unroll
        for (int tm = 0; tm < 4; tm++)
            #pragma unroll
            for (int tn = 0; tn < 4; tn++) {
                acc[tm][tn] = __builtin_amdgcn_mfma_f32_16x16x32_bf16(ah[tm], bh[tn], acc[tm][tn], 0, 0, 0);
                acc[tm][tn] = __builtin_amdgcn_mfma_f32_16x16x32_bf16(ah[tm], bl[tn], acc[tm][tn], 0, 0, 0);
                acc[tm][tn] = __builtin_amdgcn_mfma_f32_16x16x32_bf16(al[tm], bh[tn], acc[tm][tn], 0, 0, 0);
            }
    }

    const int colb = brow + wc * 64 + (lane & 15);
    const int rowb = arow + wr * 64 + (lane >> 4) * 4;
    #pragma unroll
    for (int tn = 0; tn < 4; tn++) {
        const int col = colb + tn * 16;
        const float nj = norms[col];
        #pragma unroll
        for (int tm = 0; tm < 4; tm++) {
            #pragma unroll
            for (int r = 0; r < 4; r++) {
                const int row = rowb + tm * 16 + r;
                float d = norms[row] + nj - 2.0f * acc[tm][tn][r];
                if (row == col) d += 1e10f;
                Dm[(size_t)(row - r0) * N_CELLS + col] = d;
            }
        }
    }
}

// ---------- shared tail: kth-order-statistic + masked-softmax entropy ----------
// NT = block size (multiple of 64). lst: per-thread sorted top-15 (all finite
// when N_CELLS/NT >= 15).
template<int NT>
__device__ __forceinline__ void finish_row(const float* rowb,
                                           float lst[15],
                                           const int* __restrict__ labels,
                                           float* __restrict__ out) {
    constexpr int WAVES = NT / 64;
    __shared__ float w0s[WAVES], w14s[WAVES];
    __shared__ int cnt;
    __shared__ float zz[WAVES], r0s[WAVES], r1s[WAVES], r2s[WAVES];

    const int t = threadIdx.x;
    const int lane = t & 63, wave = t >> 6;

    float m0 = lst[0], m14 = lst[14];
    #pragma unroll
    for (int off = 32; off > 0; off >>= 1) {
        m0  = fminf(m0,  __shfl_down(m0,  off, 64));
        m14 = fminf(m14, __shfl_down(m14, off, 64));
    }
    if (lane == 0) { w0s[wave] = m0; w14s[wave] = m14; }
    __syncthreads();
    float dmin = w0s[0], ub = w14s[0];
    #pragma unroll
    for (int i = 1; i < WAVES; i++) {
        dmin = fminf(dmin, w0s[i]);
        ub   = fminf(ub,   w14s[i]);
    }

    // Exact 15th order statistic: bit-space binary search, counting among the
    // per-thread top-15 register candidates (float compares vs finv(mid)).
    unsigned lo = fkey(dmin), hi = fkey(ub);
    int iter = 0;
    while (lo < hi && iter < 34) {
        iter++;
        const unsigned mid = lo + ((hi - lo) >> 1);
        const float fmid = finv(mid);
        int c = 0;
        #pragma unroll
        for (int k = 0; k < 15; k++) c += (lst[k] <= fmid) ? 1 : 0;
        #pragma unroll
        for (int off = 32; off > 0; off >>= 1) c += __shfl_down(c, off, 64);
        __syncthreads();
        if (t == 0) cnt = 0;
        __syncthreads();
        if (lane == 0) atomicAdd(&cnt, c);
        __syncthreads();
        const int total = cnt;
        if (total >= 15) hi = mid; else lo = mid + 1;
    }
    const float kth = finv(hi);

    // Pass 2: Z = sum exp(dmin-d), per-label masked sums (vectorized).
    const float4* rb4 = (const float4*)rowb;
    const int4* lb4 = (const int4*)labels;
    float z = 0.f, s0 = 0.f, s1 = 0.f, s2 = 0.f;
    #pragma unroll
    for (int s = 0; s < N_CELLS / (4 * NT); s++) {
        const int idx = s * NT + t;
        const float4 d4 = rb4[idx];
        const int4 l4 = lb4[idx];
        #pragma unroll
        for (int c = 0; c < 4; c++) {
            const float d = (c == 0) ? d4.x : (c == 1) ? d4.y : (c == 2) ? d4.z : d4.w;
            const int lab = (c == 0) ? l4.x : (c == 1) ? l4.y : (c == 2) ? l4.z : l4.w;
            const float w = __expf(dmin - d);
            const float msk = 1.0f / (1.0f + __expf(d - kth));
            const float p = w * msk;
            z  += w;
            s0 += (lab == 0) ? p : 0.f;
            s1 += (lab == 1) ? p : 0.f;
            s2 += (lab == 2) ? p : 0.f;
        }
    }
    #pragma unroll
    for (int off = 32; off > 0; off >>= 1) {
        z  += __shfl_down(z,  off, 64);
        s0 += __shfl_down(s0, off, 64);
        s1 += __shfl_down(s1, off, 64);
        s2 += __shfl_down(s2, off, 64);
    }
    if (lane == 0) { zz[wave] = z; r0s[wave] = s0; r1s[wave] = s1; r2s[wave] = s2; }
    __syncthreads();
    if (t == 0) {
        float Z = 0.f, S0 = 0.f, S1 = 0.f, S2 = 0.f;
        #pragma unroll
        for (int i = 0; i < WAVES; i++) { Z += zz[i]; S0 += r0s[i]; S1 += r1s[i]; S2 += r2s[i]; }
        const float ssum = S0 + S1 + S2;
        const float denom = ssum + 1e-8f * Z;
        const float q0 = S0/denom, q1 = S1/denom, q2 = S2/denom;
        const float H = -(q0*logf(q0+1e-8f) + q1*logf(q1+1e-8f) + q2*logf(q2+1e-8f));
        const float contrib = -(H / (logf(3.0f) + 1e-8f)) * (1.0f / N_CELLS);
        atomicAdd(out, contrib);
    }
}

// ---------- kernel C: per-row loss over a materialized D chunk ----------
// 512 threads (8 waves): 4 blocks/CU with 32KB LDS -> 32 waves/CU (100% occ),
// hiding the serial top-15 insert-chain latency. 16 elems/thread (>=15 so
// lst[14] is a valid kth upper bound). float4 loads.
__global__ __launch_bounds__(512, 8) void loss_kernel(const float* __restrict__ Dm,
                                                      const int* __restrict__ labels,
                                                      float* __restrict__ out) {
    __shared__ float rowb[N_CELLS];
    const int t = threadIdx.x;
    const float4* drow4 = (const float4*)(Dm + (size_t)blockIdx.x * N_CELLS);
    float4* rowb4 = (float4*)rowb;

    float lst[15];
    #pragma unroll
    for (int k = 0; k < 15; k++) lst[k] = 3.0e38f;

    #pragma unroll
    for (int s = 0; s < N_CELLS / (4 * 512); s++) {
        const int idx = s * 512 + t;
        float4 d4 = drow4[idx];
        rowb4[idx] = d4;
        #pragma unroll
        for (int c = 0; c < 4; c++) {
            float v = (c == 0) ? d4.x : (c == 1) ? d4.y : (c == 2) ? d4.z : d4.w;
            #pragma unroll
            for (int k = 0; k < 15; k++) {
                float lo2 = fminf(lst[k], v);
                v = fmaxf(lst[k], v);
                lst[k] = lo2;
            }
        }
    }
    finish_row<512>(rowb, lst, labels, out);
}

// ---------- fallback: fully fused fp32, recomputes dots from E ----------
__global__ __launch_bounds__(512) void fused_kernel(const float* __restrict__ E,
                                                    const float* __restrict__ norms,
                                                    const int* __restrict__ labels,
                                                    float* __restrict__ out) {
    __shared__ float rowb[N_CELLS];
    __shared__ float ei[DIM];
    const int i = blockIdx.x;
    const int t = threadIdx.x;

    for (int k = t; k < DIM; k += 512) ei[k] = E[(size_t)i * DIM + k];
    __syncthreads();
    const float ni = norms[i];

    float lst[15];
    #pragma unroll
    for (int k = 0; k < 15; k++) lst[k] = 3.0e38f;

    for (int s = 0; s < N_CELLS / 512; s++) {
        const int j = s * 512 + t;
        const float* ej = E + (size_t)j * DIM;
        float dot = 0.f;
        #pragma unroll 4
        for (int k = 0; k < DIM; k += 4) {
            float4 e4 = *(const float4*)(ej + k);
            dot += ei[k]*e4.x + ei[k+1]*e4.y + ei[k+2]*e4.z + ei[k+3]*e4.w;
        }
        float d = ni + norms[j] - 2.0f * dot;
        if (j == i) d += 1e10f;
        rowb[j] = d;
        float v = d;
        #pragma unroll
        for (int k = 0; k < 15; k++) {
            float lo2 = fminf(lst[k], v);
            v = fmaxf(lst[k], v);
            lst[k] = lo2;
        }
    }
    finish_row<512>(rowb, lst, labels, out);
}

// ---------- launcher ----------
extern "C" void kernel_launch(void* const* d_in, const int* in_sizes, int n_in,
                              void* d_out, int out_size, void* d_ws, size_t ws_size,
                              hipStream_t stream) {
    const float* E = (const float*)d_in[0];
    const int* labels = (const int*)d_in[1];
    float* out = (float*)d_out;

    char* p = (char*)d_ws;
    float* norms = (float*)p;                 p += 32768;
    unsigned short* Eh = (unsigned short*)p;  p += (size_t)N_CELLS * DIM * 2;
    unsigned short* El = (unsigned short*)p;  p += (size_t)N_CELLS * DIM * 2;
    float* Dm = (float*)p;

    const size_t fixed = 32768 + 2 * (size_t)N_CELLS * DIM * 2;  // ~16.03 MB
    const size_t rowbytes = (size_t)N_CELLS * sizeof(float);     // 32 KB
    const size_t avail = (ws_size > fixed) ? (ws_size - fixed) : 0;
    int R = (int)((avail / rowbytes) / TILE) * TILE;
    if (R > 2048) R = 2048;

    norms_kernel<<<N_CELLS / 4, 256, 0, stream>>>(E, norms, out);

    if (R >= TILE) {
        convert_kernel<<<(N_CELLS * DIM) / (256 * 4), 256, 0, stream>>>(E, Eh, El);
        for (int r0 = 0; r0 < N_CELLS; r0 += R) {
            const int rows = (N_CELLS - r0 < R) ? (N_CELLS - r0) : R;
            dim3 g(N_CELLS / TILE, rows / TILE);
            dist_mfma_kernel<<<g, 256, 0, stream>>>(Eh, El, norms, Dm, r0);
            loss_kernel<<<rows, 512, 0, stream>>>(Dm, labels, out);
        }
    } else {
        fused_kernel<<<N_CELLS, 512, 0, stream>>>(E, norms, labels, out);
    }
}

// Round 5
// 472.358 us; speedup vs baseline: 1.1737x; 1.1737x over previous
//
#include <hip/hip_runtime.h>
#include <math.h>

#define N_CELLS 8192
#define DIM 512
#define TILE 128
#define CAND_CAP 512

typedef float f32x4 __attribute__((ext_vector_type(4)));
typedef short s16x8 __attribute__((ext_vector_type(8)));

#define AS1U(p) ((const __attribute__((address_space(1))) unsigned int*)(p))
#define AS3U(p) ((__attribute__((address_space(3))) unsigned int*)(p))

// ---------- helpers: order-preserving float<->uint key ----------
__device__ __forceinline__ unsigned fkey(float f) {
    unsigned u = __float_as_uint(f);
    return (u & 0x80000000u) ? ~u : (u | 0x80000000u);
}
__device__ __forceinline__ float finv(unsigned k) {
    unsigned u = (k & 0x80000000u) ? (k ^ 0x80000000u) : ~k;
    return __uint_as_float(u);
}
// round-to-nearest-even fp32 -> bf16 bits
__device__ __forceinline__ unsigned short f2bf_bits(float x) {
    unsigned u = __float_as_uint(x);
    u += 0x7fffu + ((u >> 16) & 1u);
    return (unsigned short)(u >> 16);
}

// ---------- kernel A: squared norms (exact fp32) + zero output ----------
__global__ __launch_bounds__(256) void norms_kernel(const float* __restrict__ E,
                                                    float* __restrict__ norms,
                                                    float* __restrict__ out) {
    if (blockIdx.x == 0 && threadIdx.x == 0) out[0] = 0.0f;
    const int wave = threadIdx.x >> 6, lane = threadIdx.x & 63;
    const int row = blockIdx.x * 4 + wave;
    const float4* e4 = (const float4*)(E + (size_t)row * DIM);
    float4 a = e4[lane], b = e4[lane + 64];
    float s = a.x*a.x + a.y*a.y + a.z*a.z + a.w*a.w
            + b.x*b.x + b.y*b.y + b.z*b.z + b.w*b.w;
    #pragma unroll
    for (int off = 32; off > 0; off >>= 1) s += __shfl_down(s, off, 64);
    if (lane == 0) norms[row] = s;
}

// ---------- kernel A2: fp32 -> (hi, lo) bf16 split ----------
__global__ __launch_bounds__(256) void convert_kernel(const float* __restrict__ E,
                                                      unsigned short* __restrict__ Eh,
                                                      unsigned short* __restrict__ El) {
    const int idx = (blockIdx.x * 256 + threadIdx.x) * 4;
    float4 v = *(const float4*)(E + idx);
    ushort4 h, l;
    h.x = f2bf_bits(v.x); h.y = f2bf_bits(v.y); h.z = f2bf_bits(v.z); h.w = f2bf_bits(v.w);
    l.x = f2bf_bits(v.x - __uint_as_float((unsigned)h.x << 16));
    l.y = f2bf_bits(v.y - __uint_as_float((unsigned)h.y << 16));
    l.z = f2bf_bits(v.z - __uint_as_float((unsigned)h.z << 16));
    l.w = f2bf_bits(v.w - __uint_as_float((unsigned)h.w << 16));
    *(ushort4*)(Eh + idx) = h;
    *(ushort4*)(El + idx) = l;
}

// ---------- kernel B: MFMA split-bf16 distance GEMM (row chunk) ----------
__device__ __forceinline__ s16x8 frag_ld(const unsigned short* tile, int rowbase, int lane) {
    const int row = rowbase + (lane & 15);
    const int k8 = (lane >> 4) * 8;
    return *(const s16x8*)(tile + row * 32 + k8);
}

__global__ __launch_bounds__(256) void dist_mfma_kernel(const unsigned short* __restrict__ Eh,
                                                        const unsigned short* __restrict__ El,
                                                        const float* __restrict__ norms,
                                                        float* __restrict__ Dm,
                                                        int r0) {
    __shared__ unsigned short Ah[TILE * 32];
    __shared__ unsigned short Al[TILE * 32];
    __shared__ unsigned short Bh[TILE * 32];
    __shared__ unsigned short Bl[TILE * 32];

    const int t = threadIdx.x;
    const int lane = t & 63;
    const int w = t >> 6;
    const int wr = w >> 1, wc = w & 1;

    const int arow = r0 + blockIdx.y * TILE;
    const int brow = blockIdx.x * TILE;

    const int srow = t >> 2;
    const int sk = (t & 3) * 8;

    f32x4 acc[4][4];
    #pragma unroll
    for (int a = 0; a < 4; a++)
        #pragma unroll
        for (int b = 0; b < 4; b++)
            acc[a][b] = (f32x4){0.f, 0.f, 0.f, 0.f};

    for (int k0 = 0; k0 < DIM; k0 += 32) {
        __syncthreads();
        {
            const size_t ga0 = (size_t)(arow + srow) * DIM + k0 + sk;
            const size_t gb0 = (size_t)(brow + srow) * DIM + k0 + sk;
            const size_t stp = (size_t)64 * DIM;
            __builtin_amdgcn_global_load_lds(AS1U(Eh + ga0),       AS3U((char*)Ah + t*16),        16, 0, 0);
            __builtin_amdgcn_global_load_lds(AS1U(Eh + ga0 + stp), AS3U((char*)Ah + 4096 + t*16), 16, 0, 0);
            __builtin_amdgcn_global_load_lds(AS1U(El + ga0),       AS3U((char*)Al + t*16),        16, 0, 0);
            __builtin_amdgcn_global_load_lds(AS1U(El + ga0 + stp), AS3U((char*)Al + 4096 + t*16), 16, 0, 0);
            __builtin_amdgcn_global_load_lds(AS1U(Eh + gb0),       AS3U((char*)Bh + t*16),        16, 0, 0);
            __builtin_amdgcn_global_load_lds(AS1U(Eh + gb0 + stp), AS3U((char*)Bh + 4096 + t*16), 16, 0, 0);
            __builtin_amdgcn_global_load_lds(AS1U(El + gb0),       AS3U((char*)Bl + t*16),        16, 0, 0);
            __builtin_amdgcn_global_load_lds(AS1U(El + gb0 + stp), AS3U((char*)Bl + 4096 + t*16), 16, 0, 0);
        }
        __syncthreads();

        s16x8 ah[4], al[4], bh[4], bl[4];
        #pragma unroll
        for (int tm = 0; tm < 4; tm++) {
            ah[tm] = frag_ld(Ah, wr * 64 + tm * 16, lane);
            al[tm] = frag_ld(Al, wr * 64 + tm * 16, lane);
        }
        #pragma unroll
        for (int tn = 0; tn < 4; tn++) {
            bh[tn] = frag_ld(Bh, wc * 64 + tn * 16, lane);
            bl[tn] = frag_ld(Bl, wc * 64 + tn * 16, lane);
        }
        #pragma unroll
        for (int tm = 0; tm < 4; tm++)
            #pragma unroll
            for (int tn = 0; tn < 4; tn++) {
                acc[tm][tn] = __builtin_amdgcn_mfma_f32_16x16x32_bf16(ah[tm], bh[tn], acc[tm][tn], 0, 0, 0);
                acc[tm][tn] = __builtin_amdgcn_mfma_f32_16x16x32_bf16(ah[tm], bl[tn], acc[tm][tn], 0, 0, 0);
                acc[tm][tn] = __builtin_amdgcn_mfma_f32_16x16x32_bf16(al[tm], bh[tn], acc[tm][tn], 0, 0, 0);
            }
    }

    const int colb = brow + wc * 64 + (lane & 15);
    const int rowb = arow + wr * 64 + (lane >> 4) * 4;
    #pragma unroll
    for (int tn = 0; tn < 4; tn++) {
        const int col = colb + tn * 16;
        const float nj = norms[col];
        #pragma unroll
        for (int tm = 0; tm < 4; tm++) {
            #pragma unroll
            for (int r = 0; r < 4; r++) {
                const int row = rowb + tm * 16 + r;
                float d = norms[row] + nj - 2.0f * acc[tm][tn][r];
                if (row == col) d += 1e10f;
                Dm[(size_t)(row - r0) * N_CELLS + col] = d;
            }
        }
    }
}

// ---------- kernel C: per-row loss (fast exact selection) ----------
// 512 threads, 16 elems/thread. Pass1: float4 loads + bitonic sort-16.
// kth: wave0 ballot-search over lane minima -> threshold T (>= kth, provably);
// compact sorted prefixes <= T to LDS (row top-15 provably included);
// wave0 ballot-search over <=512 candidates -> exact kth. Fallback: old
// block-wide search if candidate count out of [15, CAND_CAP].
__global__ __launch_bounds__(512, 8) void loss_kernel(const float* __restrict__ Dm,
                                                      const int* __restrict__ labels,
                                                      float* __restrict__ out) {
    __shared__ float rowb[N_CELLS];          // 32 KB
    __shared__ unsigned cand[CAND_CAP];      // 2 KB
    __shared__ float w0s[8], w14s[8];
    __shared__ int candCnt;
    __shared__ float sT, sKth;
    __shared__ float zz[8], r0s[8], r1s[8], r2s[8];

    const int t = threadIdx.x;
    const int lane = t & 63, wave = t >> 6;
    const float4* drow4 = (const float4*)(Dm + (size_t)blockIdx.x * N_CELLS);
    float4* rowb4 = (float4*)rowb;

    // ---- pass 1: load 16 elems, cache row in LDS, bitonic sort ascending ----
    float v[16];
    #pragma unroll
    for (int s = 0; s < 4; s++) {
        const int idx = s * 512 + t;
        float4 d4 = drow4[idx];
        rowb4[idx] = d4;
        v[s*4+0] = d4.x; v[s*4+1] = d4.y; v[s*4+2] = d4.z; v[s*4+3] = d4.w;
    }
    #pragma unroll
    for (int k = 2; k <= 16; k <<= 1) {
        #pragma unroll
        for (int j = k >> 1; j > 0; j >>= 1) {
            #pragma unroll
            for (int i = 0; i < 16; i++) {
                const int l = i ^ j;
                if (l > i) {
                    const bool up = ((i & k) == 0);
                    const float a = v[i], b = v[l];
                    v[i] = up ? fminf(a, b) : fmaxf(a, b);
                    v[l] = up ? fmaxf(a, b) : fminf(a, b);
                }
            }
        }
    }
    // v[0..14] = thread's top-15 (sorted); v[15] can never be in the row top-15.

    float m0 = v[0], m14 = v[14];
    #pragma unroll
    for (int off = 32; off > 0; off >>= 1) {
        m0  = fminf(m0,  __shfl_down(m0,  off, 64));
        m14 = fminf(m14, __shfl_down(m14, off, 64));
    }
    if (lane == 0) { w0s[wave] = m0; w14s[wave] = m14; }
    if (t == 0) candCnt = 0;
    __syncthreads();
    float dmin = w0s[0], ub = w14s[0];
    #pragma unroll
    for (int i = 1; i < 8; i++) { dmin = fminf(dmin, w0s[i]); ub = fminf(ub, w14s[i]); }

    // ---- stage A: wave 0 finds T = 15th smallest of its 64 lane minima ----
    if (wave == 0) {
        const unsigned mk = fkey(v[0]);
        unsigned hmax = mk;
        #pragma unroll
        for (int off = 32; off > 0; off >>= 1) {
            const unsigned o = __shfl_down(hmax, off, 64);
            hmax = (o > hmax) ? o : hmax;
        }
        hmax = __shfl(hmax, 0, 64);
        unsigned lo1 = fkey(dmin), hi1 = hmax;
        int it = 0;
        while (lo1 < hi1 && it < 34) {
            it++;
            const unsigned mid = lo1 + ((hi1 - lo1) >> 1);
            const int c = __popcll(__ballot(mk <= mid));
            if (c >= 15) hi1 = mid; else lo1 = mid + 1;
        }
        if (lane == 0) sT = finv(lo1);
    }
    __syncthreads();

    // ---- stage B: compact candidates (sorted prefix <= T) into LDS ----
    const float T = sT;
    int c = 0;
    #pragma unroll
    for (int k = 0; k < 15; k++) c += (v[k] <= T) ? 1 : 0;
    int pfx = c;
    #pragma unroll
    for (int off = 1; off < 64; off <<= 1) {
        const int y = __shfl_up(pfx, off, 64);
        if (lane >= off) pfx += y;
    }
    const int excl = pfx - c;
    const int wtot = __shfl(pfx, 63, 64);
    int base = 0;
    if (lane == 63) base = atomicAdd(&candCnt, wtot);
    base = __shfl(base, 63, 64);
    #pragma unroll
    for (int k = 0; k < 15; k++) {
        if (k < c) {
            const int wi = base + excl + k;
            if (wi < CAND_CAP) cand[wi] = fkey(v[k]);
        }
    }
    __syncthreads();
    const int n = candCnt;

    float kth;
    if (n >= 15 && n <= CAND_CAP) {
        // ---- stage C: wave 0 exact bit-search over compacted keys ----
        if (wave == 0) {
            unsigned keys[CAND_CAP / 64];
            #pragma unroll
            for (int s = 0; s < CAND_CAP / 64; s++) {
                const int idx = s * 64 + lane;
                keys[s] = (idx < n) ? cand[idx] : 0xFFFFFFFFu;
            }
            unsigned lo2 = fkey(dmin), hi2 = fkey(T);
            int it = 0;
            while (lo2 < hi2 && it < 34) {
                it++;
                const unsigned mid = lo2 + ((hi2 - lo2) >> 1);
                int cc = 0;
                #pragma unroll
                for (int s = 0; s < CAND_CAP / 64; s++) cc += (keys[s] <= mid) ? 1 : 0;
                #pragma unroll
                for (int off = 32; off > 0; off >>= 1) cc += __shfl_down(cc, off, 64);
                cc = __shfl(cc, 0, 64);
                if (cc >= 15) hi2 = mid; else lo2 = mid + 1;
            }
            if (lane == 0) sKth = finv(lo2);
        }
        __syncthreads();
        kth = sKth;
    } else {
        // ---- fallback (block-uniform, never expected): old block-wide search ----
        unsigned lo = fkey(dmin), hi = fkey(ub);
        int iter = 0;
        while (lo < hi && iter < 34) {
            iter++;
            const unsigned mid = lo + ((hi - lo) >> 1);
            const float fmid = finv(mid);
            int cc = 0;
            #pragma unroll
            for (int k = 0; k < 15; k++) cc += (v[k] <= fmid) ? 1 : 0;
            #pragma unroll
            for (int off = 32; off > 0; off >>= 1) cc += __shfl_down(cc, off, 64);
            __syncthreads();
            if (t == 0) candCnt = 0;
            __syncthreads();
            if (lane == 0) atomicAdd(&candCnt, cc);
            __syncthreads();
            const int total = candCnt;
            if (total >= 15) hi = mid; else lo = mid + 1;
        }
        kth = finv(hi);
    }

    // ---- pass 2: Z = sum exp(dmin-d), per-label masked sums ----
    const int4* lb4 = (const int4*)labels;
    float z = 0.f, s0 = 0.f, s1 = 0.f, s2 = 0.f;
    #pragma unroll
    for (int s = 0; s < 4; s++) {
        const int idx = s * 512 + t;
        const float4 d4 = rowb4[idx];
        const int4 l4 = lb4[idx];
        #pragma unroll
        for (int cc = 0; cc < 4; cc++) {
            const float d = (cc == 0) ? d4.x : (cc == 1) ? d4.y : (cc == 2) ? d4.z : d4.w;
            const int lab = (cc == 0) ? l4.x : (cc == 1) ? l4.y : (cc == 2) ? l4.z : l4.w;
            const float w = __expf(dmin - d);
            const float msk = 1.0f / (1.0f + __expf(d - kth));
            const float p = w * msk;
            z  += w;
            s0 += (lab == 0) ? p : 0.f;
            s1 += (lab == 1) ? p : 0.f;
            s2 += (lab == 2) ? p : 0.f;
        }
    }
    #pragma unroll
    for (int off = 32; off > 0; off >>= 1) {
        z  += __shfl_down(z,  off, 64);
        s0 += __shfl_down(s0, off, 64);
        s1 += __shfl_down(s1, off, 64);
        s2 += __shfl_down(s2, off, 64);
    }
    if (lane == 0) { zz[wave] = z; r0s[wave] = s0; r1s[wave] = s1; r2s[wave] = s2; }
    __syncthreads();
    if (t == 0) {
        float Z = 0.f, S0 = 0.f, S1 = 0.f, S2 = 0.f;
        #pragma unroll
        for (int i = 0; i < 8; i++) { Z += zz[i]; S0 += r0s[i]; S1 += r1s[i]; S2 += r2s[i]; }
        const float ssum = S0 + S1 + S2;
        const float denom = ssum + 1e-8f * Z;
        const float q0 = S0/denom, q1 = S1/denom, q2 = S2/denom;
        const float H = -(q0*logf(q0+1e-8f) + q1*logf(q1+1e-8f) + q2*logf(q2+1e-8f));
        const float contrib = -(H / (logf(3.0f) + 1e-8f)) * (1.0f / N_CELLS);
        atomicAdd(out, contrib);
    }
}

// ---------- old shared tail (kept only for the tiny-ws fused fallback) ----------
template<int NT>
__device__ __forceinline__ void finish_row(const float* rowb,
                                           float lst[15],
                                           const int* __restrict__ labels,
                                           float* __restrict__ out) {
    constexpr int WAVES = NT / 64;
    __shared__ float w0s[WAVES], w14s[WAVES];
    __shared__ int cnt;
    __shared__ float zz[WAVES], r0s[WAVES], r1s[WAVES], r2s[WAVES];

    const int t = threadIdx.x;
    const int lane = t & 63, wave = t >> 6;

    float m0 = lst[0], m14 = lst[14];
    #pragma unroll
    for (int off = 32; off > 0; off >>= 1) {
        m0  = fminf(m0,  __shfl_down(m0,  off, 64));
        m14 = fminf(m14, __shfl_down(m14, off, 64));
    }
    if (lane == 0) { w0s[wave] = m0; w14s[wave] = m14; }
    __syncthreads();
    float dmin = w0s[0], ub = w14s[0];
    #pragma unroll
    for (int i = 1; i < WAVES; i++) { dmin = fminf(dmin, w0s[i]); ub = fminf(ub, w14s[i]); }

    unsigned lo = fkey(dmin), hi = fkey(ub);
    int iter = 0;
    while (lo < hi && iter < 34) {
        iter++;
        const unsigned mid = lo + ((hi - lo) >> 1);
        const float fmid = finv(mid);
        int c = 0;
        #pragma unroll
        for (int k = 0; k < 15; k++) c += (lst[k] <= fmid) ? 1 : 0;
        #pragma unroll
        for (int off = 32; off > 0; off >>= 1) c += __shfl_down(c, off, 64);
        __syncthreads();
        if (t == 0) cnt = 0;
        __syncthreads();
        if (lane == 0) atomicAdd(&cnt, c);
        __syncthreads();
        const int total = cnt;
        if (total >= 15) hi = mid; else lo = mid + 1;
    }
    const float kth = finv(hi);

    const float4* rb4 = (const float4*)rowb;
    const int4* lb4 = (const int4*)labels;
    float z = 0.f, s0 = 0.f, s1 = 0.f, s2 = 0.f;
    #pragma unroll
    for (int s = 0; s < N_CELLS / (4 * NT); s++) {
        const int idx = s * NT + t;
        const float4 d4 = rb4[idx];
        const int4 l4 = lb4[idx];
        #pragma unroll
        for (int c2 = 0; c2 < 4; c2++) {
            const float d = (c2 == 0) ? d4.x : (c2 == 1) ? d4.y : (c2 == 2) ? d4.z : d4.w;
            const int lab = (c2 == 0) ? l4.x : (c2 == 1) ? l4.y : (c2 == 2) ? l4.z : l4.w;
            const float w = __expf(dmin - d);
            const float msk = 1.0f / (1.0f + __expf(d - kth));
            const float p = w * msk;
            z  += w;
            s0 += (lab == 0) ? p : 0.f;
            s1 += (lab == 1) ? p : 0.f;
            s2 += (lab == 2) ? p : 0.f;
        }
    }
    #pragma unroll
    for (int off = 32; off > 0; off >>= 1) {
        z  += __shfl_down(z,  off, 64);
        s0 += __shfl_down(s0, off, 64);
        s1 += __shfl_down(s1, off, 64);
        s2 += __shfl_down(s2, off, 64);
    }
    if (lane == 0) { zz[wave] = z; r0s[wave] = s0; r1s[wave] = s1; r2s[wave] = s2; }
    __syncthreads();
    if (t == 0) {
        float Z = 0.f, S0 = 0.f, S1 = 0.f, S2 = 0.f;
        #pragma unroll
        for (int i = 0; i < WAVES; i++) { Z += zz[i]; S0 += r0s[i]; S1 += r1s[i]; S2 += r2s[i]; }
        const float ssum = S0 + S1 + S2;
        const float denom = ssum + 1e-8f * Z;
        const float q0 = S0/denom, q1 = S1/denom, q2 = S2/denom;
        const float H = -(q0*logf(q0+1e-8f) + q1*logf(q1+1e-8f) + q2*logf(q2+1e-8f));
        const float contrib = -(H / (logf(3.0f) + 1e-8f)) * (1.0f / N_CELLS);
        atomicAdd(out, contrib);
    }
}

// ---------- fallback: fully fused fp32, recomputes dots from E ----------
__global__ __launch_bounds__(512) void fused_kernel(const float* __restrict__ E,
                                                    const float* __restrict__ norms,
                                                    const int* __restrict__ labels,
                                                    float* __restrict__ out) {
    __shared__ float rowb[N_CELLS];
    __shared__ float ei[DIM];
    const int i = blockIdx.x;
    const int t = threadIdx.x;

    for (int k = t; k < DIM; k += 512) ei[k] = E[(size_t)i * DIM + k];
    __syncthreads();
    const float ni = norms[i];

    float lst[15];
    #pragma unroll
    for (int k = 0; k < 15; k++) lst[k] = 3.0e38f;

    for (int s = 0; s < N_CELLS / 512; s++) {
        const int j = s * 512 + t;
        const float* ej = E + (size_t)j * DIM;
        float dot = 0.f;
        #pragma unroll 4
        for (int k = 0; k < DIM; k += 4) {
            float4 e4 = *(const float4*)(ej + k);
            dot += ei[k]*e4.x + ei[k+1]*e4.y + ei[k+2]*e4.z + ei[k+3]*e4.w;
        }
        float d = ni + norms[j] - 2.0f * dot;
        if (j == i) d += 1e10f;
        rowb[j] = d;
        float v = d;
        #pragma unroll
        for (int k = 0; k < 15; k++) {
            float lo2 = fminf(lst[k], v);
            v = fmaxf(lst[k], v);
            lst[k] = lo2;
        }
    }
    finish_row<512>(rowb, lst, labels, out);
}

// ---------- launcher ----------
extern "C" void kernel_launch(void* const* d_in, const int* in_sizes, int n_in,
                              void* d_out, int out_size, void* d_ws, size_t ws_size,
                              hipStream_t stream) {
    const float* E = (const float*)d_in[0];
    const int* labels = (const int*)d_in[1];
    float* out = (float*)d_out;

    char* p = (char*)d_ws;
    float* norms = (float*)p;                 p += 32768;
    unsigned short* Eh = (unsigned short*)p;  p += (size_t)N_CELLS * DIM * 2;
    unsigned short* El = (unsigned short*)p;  p += (size_t)N_CELLS * DIM * 2;
    float* Dm = (float*)p;

    const size_t fixed = 32768 + 2 * (size_t)N_CELLS * DIM * 2;  // ~16.03 MB
    const size_t rowbytes = (size_t)N_CELLS * sizeof(float);     // 32 KB
    const size_t avail = (ws_size > fixed) ? (ws_size - fixed) : 0;
    int R = (int)((avail / rowbytes) / TILE) * TILE;
    if (R > 2048) R = 2048;

    norms_kernel<<<N_CELLS / 4, 256, 0, stream>>>(E, norms, out);

    if (R >= TILE) {
        convert_kernel<<<(N_CELLS * DIM) / (256 * 4), 256, 0, stream>>>(E, Eh, El);
        for (int r0 = 0; r0 < N_CELLS; r0 += R) {
            const int rows = (N_CELLS - r0 < R) ? (N_CELLS - r0) : R;
            dim3 g(N_CELLS / TILE, rows / TILE);
            dist_mfma_kernel<<<g, 256, 0, stream>>>(Eh, El, norms, Dm, r0);
            loss_kernel<<<rows, 512, 0, stream>>>(Dm, labels, out);
        }
    } else {
        fused_kernel<<<N_CELLS, 512, 0, stream>>>(E, norms, labels, out);
    }
}

// Round 6
// 387.120 us; speedup vs baseline: 1.4321x; 1.2202x over previous
//
#include <hip/hip_runtime.h>
#include <math.h>

#define N_CELLS 8192
#define DIM 512
#define TILE 128
#define CAND_CAP 512

typedef float f32x4 __attribute__((ext_vector_type(4)));
typedef _Float16 f16x8 __attribute__((ext_vector_type(8)));

#define AS1U(p) ((const __attribute__((address_space(1))) unsigned int*)(p))
#define AS3U(p) ((__attribute__((address_space(3))) unsigned int*)(p))

// ---------- helpers: order-preserving float<->uint key ----------
__device__ __forceinline__ unsigned fkey(float f) {
    unsigned u = __float_as_uint(f);
    return (u & 0x80000000u) ? ~u : (u | 0x80000000u);
}
__device__ __forceinline__ float finv(unsigned k) {
    unsigned u = (k & 0x80000000u) ? (k ^ 0x80000000u) : ~k;
    return __uint_as_float(u);
}

// ---------- kernel A: squared norms (exact fp32) + zero output ----------
__global__ __launch_bounds__(256) void norms_kernel(const float* __restrict__ E,
                                                    float* __restrict__ norms,
                                                    float* __restrict__ out) {
    if (blockIdx.x == 0 && threadIdx.x == 0) out[0] = 0.0f;
    const int wave = threadIdx.x >> 6, lane = threadIdx.x & 63;
    const int row = blockIdx.x * 4 + wave;
    const float4* e4 = (const float4*)(E + (size_t)row * DIM);
    float4 a = e4[lane], b = e4[lane + 64];
    float s = a.x*a.x + a.y*a.y + a.z*a.z + a.w*a.w
            + b.x*b.x + b.y*b.y + b.z*b.z + b.w*b.w;
    #pragma unroll
    for (int off = 32; off > 0; off >>= 1) s += __shfl_down(s, off, 64);
    if (lane == 0) norms[row] = s;
}

// ---------- kernel A2: fp32 -> fp16 (RTNE) ----------
__global__ __launch_bounds__(256) void convert_f16_kernel(const float* __restrict__ E,
                                                          unsigned short* __restrict__ Ef) {
    const int idx = (blockIdx.x * 256 + threadIdx.x) * 8;
    float4 v0 = *(const float4*)(E + idx);
    float4 v1 = *(const float4*)(E + idx + 4);
    f16x8 h;
    h[0] = (_Float16)v0.x; h[1] = (_Float16)v0.y; h[2] = (_Float16)v0.z; h[3] = (_Float16)v0.w;
    h[4] = (_Float16)v1.x; h[5] = (_Float16)v1.y; h[6] = (_Float16)v1.z; h[7] = (_Float16)v1.w;
    *(f16x8*)(Ef + idx) = h;
}

// ---------- kernel B: single-fp16-GEMM distance matrix (row chunk) ----------
// D[gi][gj] = n_gi + n_gj - 2*dot_f16(e_i,e_j); +1e10 diagonal.
// 128x128 tile, BK=32, chunk-major LDS tile[kc][row][8] (conflict-free b128
// frag reads; global_load_lds-compatible: LDS slot == lane index).
__global__ __launch_bounds__(256) void dist_f16_kernel(const unsigned short* __restrict__ Ef,
                                                       const float* __restrict__ norms,
                                                       float* __restrict__ Dm,
                                                       int r0) {
    __shared__ unsigned short Ah[4 * TILE * 8];   // 8 KB, [kc][row][8]
    __shared__ unsigned short Bh[4 * TILE * 8];   // 8 KB

    const int t = threadIdx.x;
    const int lane = t & 63;
    const int w = t >> 6;
    const int wr = w >> 1, wc = w & 1;

    const int arow = r0 + blockIdx.y * TILE;   // global rows (i)
    const int brow = blockIdx.x * TILE;        // global cols (j)

    const int srow = t & 127;                  // staging row
    const int skc  = t >> 7;                   // staging k-chunk (0/1 per call)

    f32x4 acc[4][4];
    #pragma unroll
    for (int a = 0; a < 4; a++)
        #pragma unroll
        for (int b = 0; b < 4; b++)
            acc[a][b] = (f32x4){0.f, 0.f, 0.f, 0.f};

    const int kg = lane >> 4;      // 0..3: MFMA k-group (8 fp16 each)
    const int fr = lane & 15;      // fragment row within 16

    for (int k0 = 0; k0 < DIM; k0 += 32) {
        __syncthreads();
        {
            const size_t ga = (size_t)(arow + srow) * DIM + k0;
            const size_t gb = (size_t)(brow + srow) * DIM + k0;
            // call c covers LDS slots [c*256, c*256+256) == k-chunks {2c, 2c+1}
            __builtin_amdgcn_global_load_lds(AS1U(Ef + ga + (size_t)skc * 8),       AS3U((char*)Ah + t*16),        16, 0, 0);
            __builtin_amdgcn_global_load_lds(AS1U(Ef + ga + (size_t)(2 + skc) * 8), AS3U((char*)Ah + 4096 + t*16), 16, 0, 0);
            __builtin_amdgcn_global_load_lds(AS1U(Ef + gb + (size_t)skc * 8),       AS3U((char*)Bh + t*16),        16, 0, 0);
            __builtin_amdgcn_global_load_lds(AS1U(Ef + gb + (size_t)(2 + skc) * 8), AS3U((char*)Bh + 4096 + t*16), 16, 0, 0);
        }
        __syncthreads();

        f16x8 af[4], bf[4];
        #pragma unroll
        for (int tm = 0; tm < 4; tm++)
            af[tm] = *(const f16x8*)(Ah + (size_t)(kg * TILE + wr * 64 + tm * 16 + fr) * 8);
        #pragma unroll
        for (int tn = 0; tn < 4; tn++)
            bf[tn] = *(const f16x8*)(Bh + (size_t)(kg * TILE + wc * 64 + tn * 16 + fr) * 8);

        #pragma unroll
        for (int tm = 0; tm < 4; tm++)
            #pragma unroll
            for (int tn = 0; tn < 4; tn++)
                acc[tm][tn] = __builtin_amdgcn_mfma_f32_16x16x32_f16(af[tm], bf[tn], acc[tm][tn], 0, 0, 0);
    }

    // epilogue: C/D layout col=lane&15, row=(lane>>4)*4+reg  [m89-verified]
    const int colb = brow + wc * 64 + (lane & 15);
    const int rowb = arow + wr * 64 + (lane >> 4) * 4;
    #pragma unroll
    for (int tn = 0; tn < 4; tn++) {
        const int col = colb + tn * 16;
        const float nj = norms[col];
        #pragma unroll
        for (int tm = 0; tm < 4; tm++) {
            #pragma unroll
            for (int r = 0; r < 4; r++) {
                const int row = rowb + tm * 16 + r;
                float d = norms[row] + nj - 2.0f * acc[tm][tn][r];
                if (row == col) d += 1e10f;
                Dm[(size_t)(row - r0) * N_CELLS + col] = d;
            }
        }
    }
}

// ---------- kernel C: per-row loss (fast exact selection, unchanged R5) ----------
__global__ __launch_bounds__(512, 8) void loss_kernel(const float* __restrict__ Dm,
                                                      const int* __restrict__ labels,
                                                      float* __restrict__ out) {
    __shared__ float rowb[N_CELLS];          // 32 KB
    __shared__ unsigned cand[CAND_CAP];      // 2 KB
    __shared__ float w0s[8], w14s[8];
    __shared__ int candCnt;
    __shared__ float sT, sKth;
    __shared__ float zz[8], r0s[8], r1s[8], r2s[8];

    const int t = threadIdx.x;
    const int lane = t & 63, wave = t >> 6;
    const float4* drow4 = (const float4*)(Dm + (size_t)blockIdx.x * N_CELLS);
    float4* rowb4 = (float4*)rowb;

    // pass 1: load 16 elems, cache row in LDS, bitonic sort-16 ascending
    float v[16];
    #pragma unroll
    for (int s = 0; s < 4; s++) {
        const int idx = s * 512 + t;
        float4 d4 = drow4[idx];
        rowb4[idx] = d4;
        v[s*4+0] = d4.x; v[s*4+1] = d4.y; v[s*4+2] = d4.z; v[s*4+3] = d4.w;
    }
    #pragma unroll
    for (int k = 2; k <= 16; k <<= 1) {
        #pragma unroll
        for (int j = k >> 1; j > 0; j >>= 1) {
            #pragma unroll
            for (int i = 0; i < 16; i++) {
                const int l = i ^ j;
                if (l > i) {
                    const bool up = ((i & k) == 0);
                    const float a = v[i], b = v[l];
                    v[i] = up ? fminf(a, b) : fmaxf(a, b);
                    v[l] = up ? fmaxf(a, b) : fminf(a, b);
                }
            }
        }
    }

    float m0 = v[0], m14 = v[14];
    #pragma unroll
    for (int off = 32; off > 0; off >>= 1) {
        m0  = fminf(m0,  __shfl_down(m0,  off, 64));
        m14 = fminf(m14, __shfl_down(m14, off, 64));
    }
    if (lane == 0) { w0s[wave] = m0; w14s[wave] = m14; }
    if (t == 0) candCnt = 0;
    __syncthreads();
    float dmin = w0s[0], ub = w14s[0];
    #pragma unroll
    for (int i = 1; i < 8; i++) { dmin = fminf(dmin, w0s[i]); ub = fminf(ub, w14s[i]); }

    // stage A: wave 0 finds T = 15th smallest of its 64 lane minima
    if (wave == 0) {
        const unsigned mk = fkey(v[0]);
        unsigned hmax = mk;
        #pragma unroll
        for (int off = 32; off > 0; off >>= 1) {
            const unsigned o = __shfl_down(hmax, off, 64);
            hmax = (o > hmax) ? o : hmax;
        }
        hmax = __shfl(hmax, 0, 64);
        unsigned lo1 = fkey(dmin), hi1 = hmax;
        int it = 0;
        while (lo1 < hi1 && it < 34) {
            it++;
            const unsigned mid = lo1 + ((hi1 - lo1) >> 1);
            const int c = __popcll(__ballot(mk <= mid));
            if (c >= 15) hi1 = mid; else lo1 = mid + 1;
        }
        if (lane == 0) sT = finv(lo1);
    }
    __syncthreads();

    // stage B: compact candidates (sorted prefix <= T) into LDS
    const float T = sT;
    int c = 0;
    #pragma unroll
    for (int k = 0; k < 15; k++) c += (v[k] <= T) ? 1 : 0;
    int pfx = c;
    #pragma unroll
    for (int off = 1; off < 64; off <<= 1) {
        const int y = __shfl_up(pfx, off, 64);
        if (lane >= off) pfx += y;
    }
    const int excl = pfx - c;
    const int wtot = __shfl(pfx, 63, 64);
    int base = 0;
    if (lane == 63) base = atomicAdd(&candCnt, wtot);
    base = __shfl(base, 63, 64);
    #pragma unroll
    for (int k = 0; k < 15; k++) {
        if (k < c) {
            const int wi = base + excl + k;
            if (wi < CAND_CAP) cand[wi] = fkey(v[k]);
        }
    }
    __syncthreads();
    const int n = candCnt;

    float kth;
    if (n >= 15 && n <= CAND_CAP) {
        if (wave == 0) {
            unsigned keys[CAND_CAP / 64];
            #pragma unroll
            for (int s = 0; s < CAND_CAP / 64; s++) {
                const int idx = s * 64 + lane;
                keys[s] = (idx < n) ? cand[idx] : 0xFFFFFFFFu;
            }
            unsigned lo2 = fkey(dmin), hi2 = fkey(T);
            int it = 0;
            while (lo2 < hi2 && it < 34) {
                it++;
                const unsigned mid = lo2 + ((hi2 - lo2) >> 1);
                int cc = 0;
                #pragma unroll
                for (int s = 0; s < CAND_CAP / 64; s++) cc += (keys[s] <= mid) ? 1 : 0;
                #pragma unroll
                for (int off = 32; off > 0; off >>= 1) cc += __shfl_down(cc, off, 64);
                cc = __shfl(cc, 0, 64);
                if (cc >= 15) hi2 = mid; else lo2 = mid + 1;
            }
            if (lane == 0) sKth = finv(lo2);
        }
        __syncthreads();
        kth = sKth;
    } else {
        // fallback (block-uniform, never expected): block-wide bit search
        unsigned lo = fkey(dmin), hi = fkey(ub);
        int iter = 0;
        while (lo < hi && iter < 34) {
            iter++;
            const unsigned mid = lo + ((hi - lo) >> 1);
            const float fmid = finv(mid);
            int cc = 0;
            #pragma unroll
            for (int k = 0; k < 15; k++) cc += (v[k] <= fmid) ? 1 : 0;
            #pragma unroll
            for (int off = 32; off > 0; off >>= 1) cc += __shfl_down(cc, off, 64);
            __syncthreads();
            if (t == 0) candCnt = 0;
            __syncthreads();
            if (lane == 0) atomicAdd(&candCnt, cc);
            __syncthreads();
            const int total = candCnt;
            if (total >= 15) hi = mid; else lo = mid + 1;
        }
        kth = finv(hi);
    }

    // pass 2: Z = sum exp(dmin-d), per-label masked sums
    const int4* lb4 = (const int4*)labels;
    float z = 0.f, s0 = 0.f, s1 = 0.f, s2 = 0.f;
    #pragma unroll
    for (int s = 0; s < 4; s++) {
        const int idx = s * 512 + t;
        const float4 d4 = rowb4[idx];
        const int4 l4 = lb4[idx];
        #pragma unroll
        for (int cc = 0; cc < 4; cc++) {
            const float d = (cc == 0) ? d4.x : (cc == 1) ? d4.y : (cc == 2) ? d4.z : d4.w;
            const int lab = (cc == 0) ? l4.x : (cc == 1) ? l4.y : (cc == 2) ? l4.z : l4.w;
            const float w = __expf(dmin - d);
            const float msk = 1.0f / (1.0f + __expf(d - kth));
            const float p = w * msk;
            z  += w;
            s0 += (lab == 0) ? p : 0.f;
            s1 += (lab == 1) ? p : 0.f;
            s2 += (lab == 2) ? p : 0.f;
        }
    }
    #pragma unroll
    for (int off = 32; off > 0; off >>= 1) {
        z  += __shfl_down(z,  off, 64);
        s0 += __shfl_down(s0, off, 64);
        s1 += __shfl_down(s1, off, 64);
        s2 += __shfl_down(s2, off, 64);
    }
    if (lane == 0) { zz[wave] = z; r0s[wave] = s0; r1s[wave] = s1; r2s[wave] = s2; }
    __syncthreads();
    if (t == 0) {
        float Z = 0.f, S0 = 0.f, S1 = 0.f, S2 = 0.f;
        #pragma unroll
        for (int i = 0; i < 8; i++) { Z += zz[i]; S0 += r0s[i]; S1 += r1s[i]; S2 += r2s[i]; }
        const float ssum = S0 + S1 + S2;
        const float denom = ssum + 1e-8f * Z;
        const float q0 = S0/denom, q1 = S1/denom, q2 = S2/denom;
        const float H = -(q0*logf(q0+1e-8f) + q1*logf(q1+1e-8f) + q2*logf(q2+1e-8f));
        const float contrib = -(H / (logf(3.0f) + 1e-8f)) * (1.0f / N_CELLS);
        atomicAdd(out, contrib);
    }
}

// ---------- old shared tail (tiny-ws fused fallback only) ----------
template<int NT>
__device__ __forceinline__ void finish_row(const float* rowb,
                                           float lst[15],
                                           const int* __restrict__ labels,
                                           float* __restrict__ out) {
    constexpr int WAVES = NT / 64;
    __shared__ float w0s[WAVES], w14s[WAVES];
    __shared__ int cnt;
    __shared__ float zz[WAVES], r0s[WAVES], r1s[WAVES], r2s[WAVES];

    const int t = threadIdx.x;
    const int lane = t & 63, wave = t >> 6;

    float m0 = lst[0], m14 = lst[14];
    #pragma unroll
    for (int off = 32; off > 0; off >>= 1) {
        m0  = fminf(m0,  __shfl_down(m0,  off, 64));
        m14 = fminf(m14, __shfl_down(m14, off, 64));
    }
    if (lane == 0) { w0s[wave] = m0; w14s[wave] = m14; }
    __syncthreads();
    float dmin = w0s[0], ub = w14s[0];
    #pragma unroll
    for (int i = 1; i < WAVES; i++) { dmin = fminf(dmin, w0s[i]); ub = fminf(ub, w14s[i]); }

    unsigned lo = fkey(dmin), hi = fkey(ub);
    int iter = 0;
    while (lo < hi && iter < 34) {
        iter++;
        const unsigned mid = lo + ((hi - lo) >> 1);
        const float fmid = finv(mid);
        int c = 0;
        #pragma unroll
        for (int k = 0; k < 15; k++) c += (lst[k] <= fmid) ? 1 : 0;
        #pragma unroll
        for (int off = 32; off > 0; off >>= 1) c += __shfl_down(c, off, 64);
        __syncthreads();
        if (t == 0) cnt = 0;
        __syncthreads();
        if (lane == 0) atomicAdd(&cnt, c);
        __syncthreads();
        const int total = cnt;
        if (total >= 15) hi = mid; else lo = mid + 1;
    }
    const float kth = finv(hi);

    const float4* rb4 = (const float4*)rowb;
    const int4* lb4 = (const int4*)labels;
    float z = 0.f, s0 = 0.f, s1 = 0.f, s2 = 0.f;
    #pragma unroll
    for (int s = 0; s < N_CELLS / (4 * NT); s++) {
        const int idx = s * NT + t;
        const float4 d4 = rb4[idx];
        const int4 l4 = lb4[idx];
        #pragma unroll
        for (int c2 = 0; c2 < 4; c2++) {
            const float d = (c2 == 0) ? d4.x : (c2 == 1) ? d4.y : (c2 == 2) ? d4.z : d4.w;
            const int lab = (c2 == 0) ? l4.x : (c2 == 1) ? l4.y : (c2 == 2) ? l4.z : l4.w;
            const float w = __expf(dmin - d);
            const float msk = 1.0f / (1.0f + __expf(d - kth));
            const float p = w * msk;
            z  += w;
            s0 += (lab == 0) ? p : 0.f;
            s1 += (lab == 1) ? p : 0.f;
            s2 += (lab == 2) ? p : 0.f;
        }
    }
    #pragma unroll
    for (int off = 32; off > 0; off >>= 1) {
        z  += __shfl_down(z,  off, 64);
        s0 += __shfl_down(s0, off, 64);
        s1 += __shfl_down(s1, off, 64);
        s2 += __shfl_down(s2, off, 64);
    }
    if (lane == 0) { zz[wave] = z; r0s[wave] = s0; r1s[wave] = s1; r2s[wave] = s2; }
    __syncthreads();
    if (t == 0) {
        float Z = 0.f, S0 = 0.f, S1 = 0.f, S2 = 0.f;
        #pragma unroll
        for (int i = 0; i < WAVES; i++) { Z += zz[i]; S0 += r0s[i]; S1 += r1s[i]; S2 += r2s[i]; }
        const float ssum = S0 + S1 + S2;
        const float denom = ssum + 1e-8f * Z;
        const float q0 = S0/denom, q1 = S1/denom, q2 = S2/denom;
        const float H = -(q0*logf(q0+1e-8f) + q1*logf(q1+1e-8f) + q2*logf(q2+1e-8f));
        const float contrib = -(H / (logf(3.0f) + 1e-8f)) * (1.0f / N_CELLS);
        atomicAdd(out, contrib);
    }
}

// ---------- fallback: fully fused fp32, recomputes dots from E ----------
__global__ __launch_bounds__(512) void fused_kernel(const float* __restrict__ E,
                                                    const float* __restrict__ norms,
                                                    const int* __restrict__ labels,
                                                    float* __restrict__ out) {
    __shared__ float rowb[N_CELLS];
    __shared__ float ei[DIM];
    const int i = blockIdx.x;
    const int t = threadIdx.x;

    for (int k = t; k < DIM; k += 512) ei[k] = E[(size_t)i * DIM + k];
    __syncthreads();
    const float ni = norms[i];

    float lst[15];
    #pragma unroll
    for (int k = 0; k < 15; k++) lst[k] = 3.0e38f;

    for (int s = 0; s < N_CELLS / 512; s++) {
        const int j = s * 512 + t;
        const float* ej = E + (size_t)j * DIM;
        float dot = 0.f;
        #pragma unroll 4
        for (int k = 0; k < DIM; k += 4) {
            float4 e4 = *(const float4*)(ej + k);
            dot += ei[k]*e4.x + ei[k+1]*e4.y + ei[k+2]*e4.z + ei[k+3]*e4.w;
        }
        float d = ni + norms[j] - 2.0f * dot;
        if (j == i) d += 1e10f;
        rowb[j] = d;
        float v = d;
        #pragma unroll
        for (int k = 0; k < 15; k++) {
            float lo2 = fminf(lst[k], v);
            v = fmaxf(lst[k], v);
            lst[k] = lo2;
        }
    }
    finish_row<512>(rowb, lst, labels, out);
}

// ---------- launcher ----------
// ws: [0,32KB) norms | [32KB,+8MB) E fp16 | rest: D row-chunk (adaptive R,
// cap 4096 rows = 128 MB). Tiny-ws fallback: fused fp32 recompute.
extern "C" void kernel_launch(void* const* d_in, const int* in_sizes, int n_in,
                              void* d_out, int out_size, void* d_ws, size_t ws_size,
                              hipStream_t stream) {
    const float* E = (const float*)d_in[0];
    const int* labels = (const int*)d_in[1];
    float* out = (float*)d_out;

    char* p = (char*)d_ws;
    float* norms = (float*)p;                 p += 32768;
    unsigned short* Ef = (unsigned short*)p;  p += (size_t)N_CELLS * DIM * 2;
    float* Dm = (float*)p;

    const size_t fixed = 32768 + (size_t)N_CELLS * DIM * 2;   // ~8.4 MB
    const size_t rowbytes = (size_t)N_CELLS * sizeof(float);  // 32 KB
    const size_t avail = (ws_size > fixed) ? (ws_size - fixed) : 0;
    int R = (int)((avail / rowbytes) / TILE) * TILE;
    if (R > 4096) R = 4096;

    norms_kernel<<<N_CELLS / 4, 256, 0, stream>>>(E, norms, out);

    if (R >= TILE) {
        convert_f16_kernel<<<(N_CELLS * DIM) / (256 * 8), 256, 0, stream>>>(E, Ef);
        for (int r0 = 0; r0 < N_CELLS; r0 += R) {
            const int rows = (N_CELLS - r0 < R) ? (N_CELLS - r0) : R;
            dim3 g(N_CELLS / TILE, rows / TILE);
            dist_f16_kernel<<<g, 256, 0, stream>>>(Ef, norms, Dm, r0);
            loss_kernel<<<rows, 512, 0, stream>>>(Dm, labels, out);
        }
    } else {
        fused_kernel<<<N_CELLS, 512, 0, stream>>>(E, norms, labels, out);
    }
}